// Round 9
// baseline (514.448 us; speedup 1.0000x reference)
//
#include <hip/hip_runtime.h>
#include <hip/hip_bf16.h>
#include <math.h>

#define N_PTS 20000
#define C_IN 128
#define C_OUT 64
#define M_PTS (N_PTS*8)
#define EPS 1e-5f

typedef __attribute__((ext_vector_type(8))) short short8;
typedef __attribute__((ext_vector_type(4))) float float4v;

__device__ __forceinline__ ushort f2bf(float f){
    unsigned int i = __float_as_uint(f);
    unsigned int r = i + 0x7fffu + ((i >> 16) & 1u);
    return (ushort)(r >> 16);
}
__device__ __forceinline__ float bf2f(ushort u){ return __uint_as_float(((unsigned int)u) << 16); }
__device__ __forceinline__ float silu(float z){ return z / (1.f + expf(-z)); }

// stats layout (fp32, ws): [0..31] gn1 group sum, [32..63] gn1 group sumsq,
//                          [64..127] gn2 ch sum, [128..191] gn2 ch sumsq

// ================= K1: Wsum1 prep + Wt2 prep + pg_init + gn1_partial =================
// blocks: [0,2048) Wsum1, [2048,2480) Wt2, [2480,2608) pg_init, [2608,3120) gn1
__global__ void __launch_bounds__(256) prep_kernel(
    const float* __restrict__ W1, const float* __restrict__ W2,
    ushort* __restrict__ Wsum1, ushort* __restrict__ Wt2,
    int* __restrict__ pg, ushort* __restrict__ h, ushort* __restrict__ h2,
    const float* __restrict__ x, float* __restrict__ stats)
{
    const int b = blockIdx.x, tid = threadIdx.x;
    if (b < 2048){
        // Wsum1 layout: [o][qi][co][ci] (ci contiguous). value = sum of W1 taps with
        // neighbor-parent offset q(o,qi).
        int idx = b * 256 + tid;
        int ci = idx & 127, co = (idx >> 7) & 63, qi = (idx >> 13) & 7, o = idx >> 16;
        int bx = (o >> 2) & 1, by = (o >> 1) & 1, bz = o & 1;
        int qx = ((qi >> 2) & 1) + bx - 1;
        int qy = ((qi >> 1) & 1) + by - 1;
        int qz = (qi & 1) + bz - 1;
        float sum = 0.f;
#pragma unroll
        for (int dx = -1; dx <= 1; dx++){
            if (((bx + dx) >> 1) != qx) continue;
#pragma unroll
            for (int dy = -1; dy <= 1; dy++){
                if (((by + dy) >> 1) != qy) continue;
#pragma unroll
                for (int dz = -1; dz <= 1; dz++){
                    if (((bz + dz) >> 1) != qz) continue;
                    int t = (dx + 1) * 9 + (dy + 1) * 3 + (dz + 1);
                    sum += W1[(t * C_IN + ci) * 64 + co];
                }
            }
        }
        Wsum1[idx] = f2bf(sum);
    } else if (b < 2480){
        // Wt2 layout: [t][co][ci]
        int idx = (b - 2048) * 256 + tid;
        int ci = idx & 63, co = (idx >> 6) & 63, t = idx >> 12;
        Wt2[idx] = f2bf(W2[(t * C_OUT + ci) * 64 + co]);
    } else if (b < 2608){
        int i = (b - 2480) * 256 + tid;
        pg[i] = -1;
        if (b == 2480){
            if (tid < C_IN) h[(size_t)N_PTS * C_IN + tid] = 0;    // zero feature row (conv1)
            if (tid < C_OUT) h2[(size_t)M_PTS * C_OUT + tid] = 0; // zero feature row (conv2)
        }
    } else {
        // gn1 partial: 512 blocks
        __shared__ float ls[64];
        if (tid < 64) ls[tid] = 0.f;
        __syncthreads();
        const int g = tid & 31;
        const int r0 = (b - 2608) * 8 + (tid >> 5);
        float sum = 0.f, sq = 0.f;
        for (int r = r0; r < N_PTS; r += 4096){
            float4 v = *(const float4*)(x + (size_t)r * C_IN + g * 4);
            sum += v.x + v.y + v.z + v.w;
            sq  += v.x*v.x + v.y*v.y + v.z*v.z + v.w*v.w;
        }
        atomicAdd(&ls[g], sum);
        atomicAdd(&ls[32 + g], sq);
        __syncthreads();
        if (tid < 64) atomicAdd(&stats[tid], ls[tid]);
    }
}

// ================= K2: pg_scatter + h_compute + skip =================
// blocks: [0,79) scatter, [79,2579) h (vec4), [2579,3829) skip (16 pts/block)
__global__ void __launch_bounds__(256) mid_kernel(
    const int* __restrict__ cds, int* __restrict__ pg,
    const float* __restrict__ x, const float* __restrict__ stats,
    const float* __restrict__ g1, const float* __restrict__ b1, ushort* __restrict__ h,
    const float* __restrict__ Wsk, const float* __restrict__ bsk, float* __restrict__ s)
{
    __shared__ float w[C_IN * C_OUT];
    const int b = blockIdx.x, tid = threadIdx.x;
    if (b < 79){
        int i = b * 256 + tid;
        if (i < N_PTS){
            const int* cd = cds + i * 4;
            pg[(cd[1] * 32 + cd[2]) * 32 + cd[3]] = i;
        }
    } else if (b < 2579){
        int i = ((b - 79) * 256 + tid) * 4;
        int c0 = i & (C_IN - 1);
        int g = c0 >> 2;
        float mu = stats[g] * (1.0f / (N_PTS * 4.0f));
        float var = stats[32 + g] * (1.0f / (N_PTS * 4.0f)) - mu * mu;
        float rs = rsqrtf(var + EPS);
        float4 v = *(const float4*)(x + i);
        ushort4 o;
        o.x = f2bf(silu((v.x - mu) * rs * g1[c0+0] + b1[c0+0]));
        o.y = f2bf(silu((v.y - mu) * rs * g1[c0+1] + b1[c0+1]));
        o.z = f2bf(silu((v.z - mu) * rs * g1[c0+2] + b1[c0+2]));
        o.w = f2bf(silu((v.w - mu) * rs * g1[c0+3] + b1[c0+3]));
        *(ushort4*)(h + i) = o;
    } else {
        for (int j = tid; j < C_IN * C_OUT; j += 256) w[j] = Wsk[j];
        __syncthreads();
        int co = tid & 63, pr = tid >> 6;
        int p0 = (b - 2579) * 16 + pr * 4;
        for (int k = 0; k < 4; k++){
            int p = p0 + k;
            const float* xr = x + (size_t)p * C_IN;
            float a = bsk[co];
            for (int cb = 0; cb < C_IN; cb += 4){
                float4 v = *(const float4*)(xr + cb);
                a += v.x * w[(cb+0)*64+co] + v.y * w[(cb+1)*64+co]
                   + v.z * w[(cb+2)*64+co] + v.w * w[(cb+3)*64+co];
            }
            s[(size_t)p * C_OUT + co] = a;
        }
    }
}

#define MFMA8(A0, A1, B0, B1, B2, B3) \
    acc[0][0] = __builtin_amdgcn_mfma_f32_16x16x32_bf16(A0, B0, acc[0][0], 0, 0, 0); \
    acc[0][1] = __builtin_amdgcn_mfma_f32_16x16x32_bf16(A0, B1, acc[0][1], 0, 0, 0); \
    acc[0][2] = __builtin_amdgcn_mfma_f32_16x16x32_bf16(A0, B2, acc[0][2], 0, 0, 0); \
    acc[0][3] = __builtin_amdgcn_mfma_f32_16x16x32_bf16(A0, B3, acc[0][3], 0, 0, 0); \
    acc[1][0] = __builtin_amdgcn_mfma_f32_16x16x32_bf16(A1, B0, acc[1][0], 0, 0, 0); \
    acc[1][1] = __builtin_amdgcn_mfma_f32_16x16x32_bf16(A1, B1, acc[1][1], 0, 0, 0); \
    acc[1][2] = __builtin_amdgcn_mfma_f32_16x16x32_bf16(A1, B2, acc[1][2], 0, 0, 0); \
    acc[1][3] = __builtin_amdgcn_mfma_f32_16x16x32_bf16(A1, B3, acc[1][3], 0, 0, 0);

// ================= conv1: 8-tap parity conv over parents (LDS tap-staged, reg-dbuf) =====
// grid = 157*8; block = 128 parents x 1 parity; hf1 written PARITY-MAJOR: row = o*N + p.
__global__ void __launch_bounds__(256, 2) conv1_tap(
    const ushort* __restrict__ h, const int* __restrict__ pg,
    const int* __restrict__ coords, const ushort* __restrict__ Wsum,
    const float* __restrict__ bias, ushort* __restrict__ hf1_pm,
    float* __restrict__ statsAcc)
{
    constexpr int AS = C_IN + 8;            // 136: 2-way banks (free)
    __shared__ ushort aT[128 * AS];         // 34816 B
    __shared__ ushort bT[64 * AS];          // 17408 B
    __shared__ int rws[8][128];
    __shared__ int cxa[128], cya[128], cza[128];

    const int tid = threadIdx.x;
    const int l = tid & 63, w = tid >> 6;
    const int r16 = l & 15, qd = l >> 4;
    const int o = blockIdx.x & 7, pb = (blockIdx.x >> 3) * 128;
    const int bx = (o >> 2) & 1, by = (o >> 1) & 1, bz = o & 1;

    if (tid < 128){
        int p = pb + tid;
        if (p < N_PTS){
            cxa[tid] = coords[p*4+1]; cya[tid] = coords[p*4+2]; cza[tid] = coords[p*4+3];
        } else { cxa[tid] = -100; cya[tid] = -100; cza[tid] = -100; }
    }
    __syncthreads();
    for (int e = tid; e < 8 * 128; e += 256){
        int qi = e >> 7, r = e & 127;
        int nx = cxa[r] + ((qi >> 2) & 1) + bx - 1;
        int ny = cya[r] + ((qi >> 1) & 1) + by - 1;
        int nz = cza[r] + (qi & 1) + bz - 1;
        int row = N_PTS;
        if ((unsigned)nx < 32u && (unsigned)ny < 32u && (unsigned)nz < 32u){
            int pi = pg[(nx * 32 + ny) * 32 + nz];
            if (pi >= 0) row = pi;
        }
        rws[qi][r] = row;
    }
    __syncthreads();

    float4v acc[2][4];
#pragma unroll
    for (int i = 0; i < 2; i++)
#pragma unroll
        for (int nb = 0; nb < 4; nb++)
#pragma unroll
            for (int rg = 0; rg < 4; rg++) acc[i][nb][rg] = 0.f;

    uint4 Ar[8], Br[4];
    auto LDG = [&](int qi){
#pragma unroll
        for (int k = 0; k < 8; k++){
            int c = k * 256 + tid, r = c >> 4, sg = c & 15;
            Ar[k] = *(const uint4*)(h + (size_t)rws[qi][r] * C_IN + sg * 8);
        }
#pragma unroll
        for (int k = 0; k < 4; k++){
            int c = k * 256 + tid, co = c >> 4, sg = c & 15;
            Br[k] = *(const uint4*)(Wsum + (((size_t)o * 8 + qi) * 64 + co) * C_IN + sg * 8);
        }
    };
    auto STS = [&](){
#pragma unroll
        for (int k = 0; k < 8; k++){
            int c = k * 256 + tid, r = c >> 4, sg = c & 15;
            *(uint4*)(aT + r * AS + sg * 8) = Ar[k];
        }
#pragma unroll
        for (int k = 0; k < 4; k++){
            int c = k * 256 + tid, co = c >> 4, sg = c & 15;
            *(uint4*)(bT + co * AS + sg * 8) = Br[k];
        }
    };

    LDG(0);
    for (int t = 0; t < 8; t++){
        __syncthreads();                 // previous tap's MFMA reads done
        STS();                           // waits vmcnt for tap t's loads
        if (t < 7) LDG(t + 1);           // prefetch next tap behind MFMA phase
        __syncthreads();                 // LDS ready
#pragma unroll
        for (int kb = 0; kb < 4; kb++){
            int ko = kb * 32 + qd * 8;
            short8 a0 = *(const short8*)(aT + (w * 32 +      r16) * AS + ko);
            short8 a1 = *(const short8*)(aT + (w * 32 + 16 + r16) * AS + ko);
            short8 b0 = *(const short8*)(bT + (     r16) * AS + ko);
            short8 b1 = *(const short8*)(bT + (16 + r16) * AS + ko);
            short8 b2 = *(const short8*)(bT + (32 + r16) * AS + ko);
            short8 b3 = *(const short8*)(bT + (48 + r16) * AS + ko);
            MFMA8(a0, a1, b0, b1, b2, b3)
        }
    }

    // epilogue: C/D col=lane&15, row=quad*4+reg. Stats + LDS-staged coalesced store.
    float bsv[4] = { bias[r16], bias[16 + r16], bias[32 + r16], bias[48 + r16] };
    float ps[4] = {0,0,0,0}, pq[4] = {0,0,0,0};
    __syncthreads();                     // all waves done reading LDS
    ushort* ep = aT;                     // [128][64] bf16
#pragma unroll
    for (int rb = 0; rb < 2; rb++)
#pragma unroll
        for (int rg = 0; rg < 4; rg++){
            int rloc = w * 32 + rb * 16 + qd * 4 + rg;
            bool valid = (pb + rloc) < N_PTS;
#pragma unroll
            for (int nb = 0; nb < 4; nb++){
                float v = acc[rb][nb][rg] + bsv[nb];
                ep[rloc * 64 + nb * 16 + r16] = f2bf(v);
                if (valid){ ps[nb] += v; pq[nb] += v * v; }
            }
        }
    __syncthreads();
#pragma unroll
    for (int pass = 0; pass < 4; pass++){
        int c = pass * 256 + tid;        // 1024 chunks of 16B
        int rloc = c >> 3, sg = c & 7;
        int p = pb + rloc;
        if (p < N_PTS)
            *(uint4*)(hf1_pm + ((size_t)o * N_PTS + p) * 64 + sg * 8) =
                *(const uint4*)(ep + rloc * 64 + sg * 8);
    }
#pragma unroll
    for (int nb = 0; nb < 4; nb++){
        float s1 = ps[nb], s2 = pq[nb];
        s1 += __shfl_xor(s1, 16, 64); s2 += __shfl_xor(s2, 16, 64);
        s1 += __shfl_xor(s1, 32, 64); s2 += __shfl_xor(s2, 32, 64);
        if (qd == 0){
            atomicAdd(&statsAcc[64 + nb * 16 + r16], s1);
            atomicAdd(&statsAcc[128 + nb * 16 + r16], s2);
        }
    }
}

// ================= conv2: 27-tap child conv (LDS tap-staged, reg-dbuf) =================
// grid = 1250; block = 128 children (child-major). feat is PARITY-MAJOR h2.
__global__ void __launch_bounds__(256, 3) conv2_tap(
    const ushort* __restrict__ feat, const int* __restrict__ pg,
    const int* __restrict__ coords, const ushort* __restrict__ Wt,
    const float* __restrict__ bias, const float* __restrict__ skip,
    float* __restrict__ out)
{
    constexpr int AS = C_OUT + 8;            // 72
    __shared__ char SH[43008];
    ushort* aT = (ushort*)SH;                // 18432 B
    ushort* bT = (ushort*)(SH + 18432);      // 9216 B
    int (*rws)[128] = (int(*)[128])(SH + 27648);   // 13824 B
    int* cxa = (int*)(SH + 41472);
    int* cya = (int*)(SH + 41984);
    int* cza = (int*)(SH + 42496);

    const int tid = threadIdx.x;
    const int l = tid & 63, w = tid >> 6;
    const int r16 = l & 15, qd = l >> 4;
    const int mb = blockIdx.x * 128;

    if (tid < 128){
        int m = mb + tid, p = m >> 3, oo = m & 7;
        cxa[tid] = 2 * coords[p*4+1] + ((oo >> 2) & 1);
        cya[tid] = 2 * coords[p*4+2] + ((oo >> 1) & 1);
        cza[tid] = 2 * coords[p*4+3] + (oo & 1);
    }
    __syncthreads();
    for (int e = tid; e < 27 * 128; e += 256){
        int t = e >> 7, r = e & 127;
        int cx = cxa[r] + t / 9 - 1, cy = cya[r] + (t / 3) % 3 - 1, cz = cza[r] + t % 3 - 1;
        int row = M_PTS;
        if ((unsigned)cx < 64u && (unsigned)cy < 64u && (unsigned)cz < 64u){
            int pi = pg[((cx >> 1) * 32 + (cy >> 1)) * 32 + (cz >> 1)];
            if (pi >= 0) row = (((cx & 1) << 2) | ((cy & 1) << 1) | (cz & 1)) * N_PTS + pi;
        }
        rws[t][r] = row;
    }
    __syncthreads();

    float4v acc[2][4];
#pragma unroll
    for (int i = 0; i < 2; i++)
#pragma unroll
        for (int nb = 0; nb < 4; nb++)
#pragma unroll
            for (int rg = 0; rg < 4; rg++) acc[i][nb][rg] = 0.f;

    uint4 Ar[4], Br[2];
    auto LDG = [&](int t){
#pragma unroll
        for (int k = 0; k < 4; k++){
            int c = k * 256 + tid, r = c >> 3, sg = c & 7;
            Ar[k] = *(const uint4*)(feat + (size_t)rws[t][r] * C_OUT + sg * 8);
        }
#pragma unroll
        for (int k = 0; k < 2; k++){
            int c = k * 256 + tid, co = c >> 3, sg = c & 7;
            Br[k] = *(const uint4*)(Wt + ((size_t)t * 64 + co) * C_OUT + sg * 8);
        }
    };
    auto STS = [&](){
#pragma unroll
        for (int k = 0; k < 4; k++){
            int c = k * 256 + tid, r = c >> 3, sg = c & 7;
            *(uint4*)(aT + r * AS + sg * 8) = Ar[k];
        }
#pragma unroll
        for (int k = 0; k < 2; k++){
            int c = k * 256 + tid, co = c >> 3, sg = c & 7;
            *(uint4*)(bT + co * AS + sg * 8) = Br[k];
        }
    };

    LDG(0);
    for (int t = 0; t < 27; t++){
        __syncthreads();
        STS();
        if (t < 26) LDG(t + 1);
        __syncthreads();
#pragma unroll
        for (int kb = 0; kb < 2; kb++){
            int ko = kb * 32 + qd * 8;
            short8 a0 = *(const short8*)(aT + (w * 32 +      r16) * AS + ko);
            short8 a1 = *(const short8*)(aT + (w * 32 + 16 + r16) * AS + ko);
            short8 b0 = *(const short8*)(bT + (     r16) * AS + ko);
            short8 b1 = *(const short8*)(bT + (16 + r16) * AS + ko);
            short8 b2 = *(const short8*)(bT + (32 + r16) * AS + ko);
            short8 b3 = *(const short8*)(bT + (48 + r16) * AS + ko);
            MFMA8(a0, a1, b0, b1, b2, b3)
        }
    }

    // epilogue: stage fp32 in LDS, coalesced float4 store + skip
    __syncthreads();                       // all waves done with LDS
    float* ep = (float*)SH + w * 2048;     // 32 x 64 f32 per wave
    float bsv[4] = { bias[r16], bias[16 + r16], bias[32 + r16], bias[48 + r16] };
#pragma unroll
    for (int rb = 0; rb < 2; rb++)
#pragma unroll
        for (int rg = 0; rg < 4; rg++){
            int rloc = rb * 16 + qd * 4 + rg;
#pragma unroll
            for (int nb = 0; nb < 4; nb++)
                ep[rloc * 64 + nb * 16 + r16] = acc[rb][nb][rg] + bsv[nb];
        }
#pragma unroll
    for (int pass = 0; pass < 8; pass++){
        int c = pass * 64 + l;             // wave-local: 512 chunks of 16B
        int rloc = c >> 4, coff = (c & 15) * 4;
        int mm = mb + w * 32 + rloc;
        float4 v = *(const float4*)(ep + rloc * 64 + coff);
        const float* sk = skip + (size_t)(mm >> 3) * 64 + coff;
        v.x += sk[0]; v.y += sk[1]; v.z += sk[2]; v.w += sk[3];
        *(float4*)(out + (size_t)mm * 64 + coff) = v;
    }
}

// ================= K4: h2 = silu(gn2(hf1_bf16)) -> bf16 (both parity-major) =========
__global__ void __launch_bounds__(256) h2_kernel(
    const ushort* __restrict__ hf1, const float* __restrict__ stats,
    const float* __restrict__ gg, const float* __restrict__ gb, ushort* __restrict__ h2)
{
    int i = (blockIdx.x * 256 + threadIdx.x) * 4;
    if (i >= M_PTS * C_OUT) return;
    int c0 = i & (C_OUT - 1);
    const float inv = 1.0f / (M_PTS * 2.0f);
    float muA = (stats[64 + c0] + stats[64 + c0 + 1]) * inv;
    float vA  = (stats[128 + c0] + stats[128 + c0 + 1]) * inv - muA * muA;
    float rsA = rsqrtf(vA + EPS);
    float muB = (stats[64 + c0 + 2] + stats[64 + c0 + 3]) * inv;
    float vB  = (stats[128 + c0 + 2] + stats[128 + c0 + 3]) * inv - muB * muB;
    float rsB = rsqrtf(vB + EPS);
    ushort4 u = *(const ushort4*)(hf1 + i);
    ushort4 o;
    o.x = f2bf(silu((bf2f(u.x) - muA) * rsA * gg[c0+0] + gb[c0+0]));
    o.y = f2bf(silu((bf2f(u.y) - muA) * rsA * gg[c0+1] + gb[c0+1]));
    o.z = f2bf(silu((bf2f(u.z) - muB) * rsB * gg[c0+2] + gb[c0+2]));
    o.w = f2bf(silu((bf2f(u.w) - muB) * rsB * gg[c0+3] + gb[c0+3]));
    *(ushort4*)(h2 + i) = o;
}

extern "C" void kernel_launch(void* const* d_in, const int* in_sizes, int n_in,
                              void* d_out, int out_size, void* d_ws, size_t ws_size,
                              hipStream_t stream){
    const float* x   = (const float*)d_in[0];
    const int*   cds = (const int*)  d_in[1];
    const float* g1  = (const float*)d_in[2];
    const float* b1  = (const float*)d_in[3];
    const float* W1  = (const float*)d_in[4];
    const float* bb1 = (const float*)d_in[5];
    const float* g2  = (const float*)d_in[6];
    const float* b2  = (const float*)d_in[7];
    const float* W2  = (const float*)d_in[8];
    const float* bb2 = (const float*)d_in[9];
    const float* Wsk = (const float*)d_in[10];
    const float* bsk = (const float*)d_in[11];
    float* out = (float*)d_out;
    char* ws = (char*)d_ws;

    // workspace layout (16B-aligned)
    float*  stats = (float*) (ws);                 // 192 f32 (zeroed via memsetAsync)
    int*    pg    = (int*)   (ws + 1024);          // 131072 B -> 132096
    ushort* h     = (ushort*)(ws + 132096);        // (N+1)*128 bf16 -> 5,252,352
    ushort* h2    = (ushort*)(ws + 5252352);       // (M+1)*64 bf16 (parity-major) -> 25,732,480
    float*  s     = (float*) (ws + 25732480);      // N*64 f32 -> 30,852,480
    ushort* Wsum1 = (ushort*)(ws + 30852480);      // 8*8*64*128 bf16 = 1,048,576 -> 31,901,056
    ushort* Wt2   = (ushort*)(ws + 31901056);      // 27*64*64 bf16 = 221,184 -> 32,122,240
    // hf1 (bf16, parity-major M*64) lives in d_out between conv1 and h2_kernel.

    hipMemsetAsync(stats, 0, 192 * sizeof(float), stream);
    prep_kernel<<<3120, 256, 0, stream>>>(W1, W2, Wsum1, Wt2, pg, h, h2, x, stats);
    mid_kernel<<<3829, 256, 0, stream>>>(cds, pg, x, stats, g1, b1, h, Wsk, bsk, s);
    conv1_tap<<<157 * 8, 256, 0, stream>>>(h, pg, cds, Wsum1, bb1, (ushort*)d_out, stats);
    h2_kernel<<<10000, 256, 0, stream>>>((const ushort*)d_out, stats, g2, b2, h2);
    conv2_tap<<<1250, 256, 0, stream>>>(h2, pg, cds, Wt2, bb2, s, out);
}